// Round 2
// baseline (439.124 us; speedup 1.0000x reference)
//
#include <hip/hip_runtime.h>

// Problem constants (from reference setup_inputs): B=4, D=2048, L=8192, K=3, pad=1
constexpr int B = 4;
constexpr int D = 2048;
constexpr int L = 8192;
constexpr int KW = 3;
constexpr int PAD = 1;
constexpr int L_OUT = L + 2 * PAD - KW + 1;  // 8192

typedef float f4 __attribute__((ext_vector_type(4)));

// 8 floats per thread. A wave (64 lanes) covers 512 contiguous floats of one
// row; 8192/512 = 16 waves per row, so waves never straddle rows and the
// per-channel weights are wave-uniform (scalar loads via readfirstlane).
// Halo elements come from neighbor lanes via shuffle; only lane 0 / lane 63
// issue a 1-line predicated global load at the wave edge.
__global__ __launch_bounds__(256) void dwconv1d_k3(
    const float* __restrict__ in,    // [B, D, L]
    const float* __restrict__ w,     // [D, 3]
    const float* __restrict__ bias,  // [D]
    float* __restrict__ out)         // [B, D, L_OUT]
{
    const int gid  = blockIdx.x * 256 + threadIdx.x;
    const int row  = gid >> 10;          // 1024 threads per row (8192/8)
    const int t    = gid & 1023;
    const int l    = t << 3;             // starting float index in row
    const int lane = threadIdx.x & 63;

    const float* __restrict__ rowp = in + (size_t)row * L;

    // Two aligned 16B vector loads = 32B/thread (streaming, no reuse -> nt)
    f4 a = __builtin_nontemporal_load((const f4*)(rowp + l));
    f4 b = __builtin_nontemporal_load((const f4*)(rowp + l + 4));

    // Halos from neighbor lanes (wave is contiguous within the row)
    float left  = __shfl_up(b.w, 1);     // prev thread's in[l+7] == my in[l-1]
    float right = __shfl_down(a.x, 1);   // next thread's in[l]   == my in[l+8]
    if (lane == 0)  left  = (l > 0)     ? rowp[l - 1] : 0.0f;  // zero-pad at row start
    if (lane == 63) right = (l + 8 < L) ? rowp[l + 8] : 0.0f;  // zero-pad at row end

    // Wave-uniform channel index -> scalar (s_load) weight/bias reads
    const int d  = __builtin_amdgcn_readfirstlane(row & (D - 1));
    const float w0 = w[d * KW + 0];
    const float w1 = w[d * KW + 1];
    const float w2 = w[d * KW + 2];
    const float bv = bias[d];

    // out[l+j] = bias + in[l+j-1]*w0 + in[l+j]*w1 + in[l+j+1]*w2
    // Accumulation order matches reference (bias, k=0,1,2).
    f4 o0, o1;
    o0.x = fmaf(a.y,  w2, fmaf(a.x, w1, fmaf(left, w0, bv)));
    o0.y = fmaf(a.z,  w2, fmaf(a.y, w1, fmaf(a.x,  w0, bv)));
    o0.z = fmaf(a.w,  w2, fmaf(a.z, w1, fmaf(a.y,  w0, bv)));
    o0.w = fmaf(b.x,  w2, fmaf(a.w, w1, fmaf(a.z,  w0, bv)));
    o1.x = fmaf(b.y,  w2, fmaf(b.x, w1, fmaf(a.w,  w0, bv)));
    o1.y = fmaf(b.z,  w2, fmaf(b.y, w1, fmaf(b.x,  w0, bv)));
    o1.z = fmaf(b.w,  w2, fmaf(b.z, w1, fmaf(b.y,  w0, bv)));
    o1.w = fmaf(right, w2, fmaf(b.w, w1, fmaf(b.z, w0, bv)));

    float* __restrict__ outp = out + (size_t)row * L_OUT + l;
    __builtin_nontemporal_store(o0, (f4*)(outp));
    __builtin_nontemporal_store(o1, (f4*)(outp + 4));
}

extern "C" void kernel_launch(void* const* d_in, const int* in_sizes, int n_in,
                              void* d_out, int out_size, void* d_ws, size_t ws_size,
                              hipStream_t stream) {
    const float* in   = (const float*)d_in[0];
    const float* w    = (const float*)d_in[1];
    const float* bias = (const float*)d_in[2];
    // d_in[3] is padding (int scalar) — fixed at 1 for this problem.
    float* out = (float*)d_out;

    constexpr int total_threads = B * D * (L / 8);  // 8,388,608
    constexpr int block = 256;
    constexpr int grid  = total_threads / block;    // 32,768 blocks

    dwconv1d_k3<<<grid, block, 0, stream>>>(in, w, bias, out);
}